// Round 1
// baseline (1458.756 us; speedup 1.0000x reference)
//
#include <hip/hip_runtime.h>
#include <hip/hip_bf16.h>
#include <math.h>

#define LNUM 12
#define BNUM 8
#define DNUM 2048
#define VNUM 32000
#define HNUM 64
#define HDNUM 64
#define GNUM 8
#define NNUM 128
#define KNUM 4
#define INUM (HNUM*HDNUM)              /* 4096 */
#define CONVNUM (INUM + 2*GNUM*NNUM)   /* 6144 */
#define PNUM (INUM + CONVNUM + HNUM)   /* 14304 */

#define IP_PB 14
#define IP_DC 16
#define IP_CHUNK (DNUM/IP_DC)          /* 128 */
#define OP_DC 64
#define OP_CHUNK (INUM/OP_DC)          /* 64 */

__device__ __forceinline__ float sigmoidf_(float x){ return 1.f/(1.f+expf(-x)); }

// ---------------- embedding gather ----------------
__global__ void k_embed(const int* __restrict__ ids, const float* __restrict__ emb,
                        float* __restrict__ h){
  int b = blockIdx.x; int t = threadIdx.x;
  const float* src = emb + (size_t)ids[b]*DNUM;
  float* dst = h + (size_t)b*DNUM;
  for (int d = t*4; d < DNUM; d += 256*4)
    *(float4*)(dst + d) = *(const float4*)(src + d);
}

// ---------------- rmsnorm (row length n, weights w) ----------------
__global__ void k_rmsnorm(const float* __restrict__ in, float* __restrict__ outp,
                          const float* __restrict__ w, int n){
  int b = blockIdx.x, t = threadIdx.x;
  const float* row = in + (size_t)b*n;
  float s = 0.f;
  for (int i = t*4; i < n; i += 1024){
    float4 v = *(const float4*)(row + i);
    s += v.x*v.x + v.y*v.y + v.z*v.z + v.w*v.w;
  }
  s += __shfl_xor(s,32); s += __shfl_xor(s,16); s += __shfl_xor(s,8);
  s += __shfl_xor(s,4);  s += __shfl_xor(s,2);  s += __shfl_xor(s,1);
  __shared__ float red[4];
  __shared__ float inv_s;
  if ((t & 63) == 0) red[t>>6] = s;
  __syncthreads();
  if (t == 0) inv_s = rsqrtf((red[0]+red[1]+red[2]+red[3])/(float)n + 1e-5f);
  __syncthreads();
  float inv = inv_s;
  float* orow = outp + (size_t)b*n;
  for (int i = t*4; i < n; i += 1024){
    float4 v = *(const float4*)(row + i);
    float4 wv = *(const float4*)(w + i);
    v.x *= inv*wv.x; v.y *= inv*wv.y; v.z *= inv*wv.z; v.w *= inv*wv.w;
    *(float4*)(orow + i) = v;
  }
}

// ---------------- in_proj GEMV, split-K partials ----------------
__global__ __launch_bounds__(256) void k_inproj(const float* __restrict__ hn,
                                                const float* __restrict__ W,
                                                float* __restrict__ part){
  int t = threadIdx.x;
  int pb = blockIdx.x, dc = blockIdx.y;
  __shared__ float xs[BNUM][IP_CHUNK];
  for (int i = t; i < BNUM*IP_CHUNK; i += 256){
    int b = i >> 7, dl = i & (IP_CHUNK-1);
    xs[b][dl] = hn[b*DNUM + dc*IP_CHUNK + dl];
  }
  __syncthreads();
  int p0 = pb*1024 + t*4;
  if (p0 >= PNUM) return;
  float4 acc[BNUM];
  #pragma unroll
  for (int b = 0; b < BNUM; ++b) acc[b] = make_float4(0.f,0.f,0.f,0.f);
  const float* wp = W + (size_t)(dc*IP_CHUNK)*PNUM + p0;
  #pragma unroll 8
  for (int dl = 0; dl < IP_CHUNK; ++dl){
    float4 w4 = *(const float4*)wp;
    wp += PNUM;
    #pragma unroll
    for (int b = 0; b < BNUM; ++b){
      float xv = xs[b][dl];
      acc[b].x += xv*w4.x; acc[b].y += xv*w4.y; acc[b].z += xv*w4.z; acc[b].w += xv*w4.w;
    }
  }
  #pragma unroll
  for (int b = 0; b < BNUM; ++b)
    *(float4*)(part + (size_t)(dc*BNUM + b)*PNUM + p0) = acc[b];
}

__global__ void k_reduce_proj(const float* __restrict__ part, float* __restrict__ proj){
  int idx = blockIdx.x*256 + threadIdx.x;
  if (idx >= BNUM*PNUM) return;
  float s = 0.f;
  #pragma unroll
  for (int dc = 0; dc < IP_DC; ++dc) s += part[(size_t)dc*BNUM*PNUM + idx];
  proj[idx] = s;
}

// ---------------- conv shift + silu ----------------
__global__ void k_conv(const float* __restrict__ cs_in, const float* __restrict__ proj,
                       const float* __restrict__ cw, const float* __restrict__ cb,
                       float* __restrict__ cs_out, float* __restrict__ convout){
  int idx = blockIdx.x*256 + threadIdx.x;   // b*CONV + c
  if (idx >= BNUM*CONVNUM) return;
  int b = idx / CONVNUM, c = idx % CONVNUM;
  float4 s = *(const float4*)(cs_in + (size_t)idx*KNUM);
  float ni = proj[b*PNUM + INUM + c];
  float4 ns = make_float4(s.y, s.z, s.w, ni);
  *(float4*)(cs_out + (size_t)idx*KNUM) = ns;
  float4 w = *(const float4*)(cw + c*KNUM);
  float co = ns.x*w.x + ns.y*w.y + ns.z*w.z + ns.w*w.w + cb[c];
  convout[idx] = co * sigmoidf_(co);
}

// ---------------- SSM state update ----------------
__global__ __launch_bounds__(256) void k_ssm(const float* __restrict__ ss_in,
                                             const float* __restrict__ proj,
                                             const float* __restrict__ convout,
                                             const float* __restrict__ dt_bias,
                                             const float* __restrict__ A_log,
                                             const float* __restrict__ D_param,
                                             float* __restrict__ ss_out,
                                             float* __restrict__ y){
  int b = blockIdx.x >> 6, h = blockIdx.x & 63;
  int t = threadIdx.x;
  __shared__ float Bs[NNUM], Cs[NNUM];
  int g = h >> 3;
  if (t < NNUM) Bs[t] = convout[b*CONVNUM + INUM + g*NNUM + t];
  else          Cs[t-NNUM] = convout[b*CONVNUM + INUM + GNUM*NNUM + g*NNUM + (t-NNUM)];
  __syncthreads();
  float dtr = proj[b*PNUM + INUM + CONVNUM + h] + dt_bias[h];
  float dt = (dtr > 20.f) ? dtr : log1pf(expf(dtr));
  dt = fminf(fmaxf(dt, 0.f), 10000.f);
  float A  = -expf(A_log[h]);
  float dA = expf(dt*A);
  float dp = D_param[h];
  int r = t & 31, a = t >> 5;
  float4 Bv = *(float4*)&Bs[r*4];
  float4 Cv = *(float4*)&Cs[r*4];
  const float* sin_ = ss_in  + (size_t)(b*HNUM + h)*HDNUM*NNUM;
  float*       sout = ss_out + (size_t)(b*HNUM + h)*HDNUM*NNUM;
  #pragma unroll
  for (int k = 0; k < 8; ++k){
    int hd = k*8 + a;
    float xv = convout[b*CONVNUM + h*HDNUM + hd];
    float coef = dt * xv;
    int off = k*1024 + t*4;
    float4 s4 = *(const float4*)(sin_ + off);
    float4 ns;
    ns.x = s4.x*dA + coef*Bv.x;
    ns.y = s4.y*dA + coef*Bv.y;
    ns.z = s4.z*dA + coef*Bv.z;
    ns.w = s4.w*dA + coef*Bv.w;
    *(float4*)(sout + off) = ns;
    float yp = ns.x*Cv.x + ns.y*Cv.y + ns.z*Cv.z + ns.w*Cv.w;
    yp += __shfl_xor(yp,1); yp += __shfl_xor(yp,2); yp += __shfl_xor(yp,4);
    yp += __shfl_xor(yp,8); yp += __shfl_xor(yp,16);
    if (r == 0) y[b*INUM + h*HDNUM + hd] = yp + xv*dp;
  }
}

// ---------------- gated RMSNorm ----------------
__global__ void k_gatednorm(const float* __restrict__ proj, const float* __restrict__ y,
                            const float* __restrict__ gw, float* __restrict__ yn){
  int b = blockIdx.x, t = threadIdx.x;
  float s = 0.f;
  for (int i = t; i < INUM; i += 256){
    float gv = proj[b*PNUM + i];
    float v = y[b*INUM + i] * gv * sigmoidf_(gv);
    yn[b*INUM + i] = v;
    s += v*v;
  }
  s += __shfl_xor(s,32); s += __shfl_xor(s,16); s += __shfl_xor(s,8);
  s += __shfl_xor(s,4);  s += __shfl_xor(s,2);  s += __shfl_xor(s,1);
  __shared__ float red[4];
  __shared__ float inv_s;
  if ((t & 63) == 0) red[t>>6] = s;
  __syncthreads();
  if (t == 0) inv_s = rsqrtf((red[0]+red[1]+red[2]+red[3])/(float)INUM + 1e-5f);
  __syncthreads();
  float inv = inv_s;
  for (int i = t; i < INUM; i += 256)
    yn[b*INUM + i] = yn[b*INUM + i] * inv * gw[i];
}

// ---------------- out_proj GEMV, split-K partials ----------------
__global__ __launch_bounds__(128) void k_outproj(const float* __restrict__ yn,
                                                 const float* __restrict__ W,
                                                 float* __restrict__ part){
  int t = threadIdx.x;
  int pb = blockIdx.x, ic = blockIdx.y;   // pb 0..3, ic 0..63
  __shared__ float xs[BNUM][OP_CHUNK];
  for (int i = t; i < BNUM*OP_CHUNK; i += 128){
    int b = i >> 6, il = i & (OP_CHUNK-1);
    xs[b][il] = yn[b*INUM + ic*OP_CHUNK + il];
  }
  __syncthreads();
  int d0 = pb*512 + t*4;
  float4 acc[BNUM];
  #pragma unroll
  for (int b = 0; b < BNUM; ++b) acc[b] = make_float4(0.f,0.f,0.f,0.f);
  const float* wp = W + (size_t)(ic*OP_CHUNK)*DNUM + d0;
  #pragma unroll 8
  for (int il = 0; il < OP_CHUNK; ++il){
    float4 w4 = *(const float4*)wp;
    wp += DNUM;
    #pragma unroll
    for (int b = 0; b < BNUM; ++b){
      float xv = xs[b][il];
      acc[b].x += xv*w4.x; acc[b].y += xv*w4.y; acc[b].z += xv*w4.z; acc[b].w += xv*w4.w;
    }
  }
  #pragma unroll
  for (int b = 0; b < BNUM; ++b)
    *(float4*)(part + (size_t)(ic*BNUM + b)*DNUM + d0) = acc[b];
}

__global__ void k_reduce_out(const float* __restrict__ part, float* __restrict__ h){
  int idx = blockIdx.x*256 + threadIdx.x;   // < B*D
  float s = h[idx];
  #pragma unroll
  for (int ic = 0; ic < OP_DC; ++ic) s += part[(size_t)ic*BNUM*DNUM + idx];
  h[idx] = s;
}

// ---------------- lm_head: wave-per-4-rows dot ----------------
__global__ __launch_bounds__(256) void k_lmhead(const float* __restrict__ hf,
                                                const float* __restrict__ Wl,
                                                float* __restrict__ logits){
  __shared__ float hs[BNUM*DNUM];   // 64KB
  int t = threadIdx.x;
  for (int i = t*4; i < BNUM*DNUM; i += 1024)
    *(float4*)(hs + i) = *(const float4*)(hf + i);
  __syncthreads();
  int wv = t >> 6, lane = t & 63;
  int v0 = (blockIdx.x*4 + wv)*4;
  float acc[4][BNUM];
  #pragma unroll
  for (int u = 0; u < 4; ++u)
    #pragma unroll
    for (int b = 0; b < BNUM; ++b) acc[u][b] = 0.f;
  #pragma unroll
  for (int j = 0; j < 8; ++j){
    int dbase = j*256 + lane*4;
    float4 w0 = *(const float4*)(Wl + (size_t)(v0+0)*DNUM + dbase);
    float4 w1 = *(const float4*)(Wl + (size_t)(v0+1)*DNUM + dbase);
    float4 w2 = *(const float4*)(Wl + (size_t)(v0+2)*DNUM + dbase);
    float4 w3 = *(const float4*)(Wl + (size_t)(v0+3)*DNUM + dbase);
    #pragma unroll
    for (int b = 0; b < BNUM; ++b){
      float4 hv = *(const float4*)(hs + b*DNUM + dbase);
      acc[0][b] += w0.x*hv.x + w0.y*hv.y + w0.z*hv.z + w0.w*hv.w;
      acc[1][b] += w1.x*hv.x + w1.y*hv.y + w1.z*hv.z + w1.w*hv.w;
      acc[2][b] += w2.x*hv.x + w2.y*hv.y + w2.z*hv.z + w2.w*hv.w;
      acc[3][b] += w3.x*hv.x + w3.y*hv.y + w3.z*hv.z + w3.w*hv.w;
    }
  }
  #pragma unroll
  for (int u = 0; u < 4; ++u)
    #pragma unroll
    for (int b = 0; b < BNUM; ++b){
      float s = acc[u][b];
      s += __shfl_xor(s,32); s += __shfl_xor(s,16); s += __shfl_xor(s,8);
      s += __shfl_xor(s,4);  s += __shfl_xor(s,2);  s += __shfl_xor(s,1);
      if (lane == 0) logits[(size_t)b*VNUM + v0 + u] = s;
    }
}

extern "C" void kernel_launch(void* const* d_in, const int* in_sizes, int n_in,
                              void* d_out, int out_size, void* d_ws, size_t ws_size,
                              hipStream_t stream){
  const int*   ids         = (const int*)d_in[0];
  const float* conv_states = (const float*)d_in[1];
  const float* ssm_states  = (const float*)d_in[2];
  const float* emb         = (const float*)d_in[3];
  const float* norm_w      = (const float*)d_in[4];
  const float* in_proj_w   = (const float*)d_in[5];
  const float* conv_w      = (const float*)d_in[6];
  const float* conv_b      = (const float*)d_in[7];
  const float* dt_bias     = (const float*)d_in[8];
  const float* A_log       = (const float*)d_in[9];
  const float* D_param     = (const float*)d_in[10];
  const float* gn_w        = (const float*)d_in[11];
  const float* out_proj_w  = (const float*)d_in[12];
  const float* norm_f_w    = (const float*)d_in[13];
  const float* lm_head_w   = (const float*)d_in[14];

  float* out         = (float*)d_out;
  float* logits      = out;
  float* conv_out_st = out + (size_t)BNUM*VNUM;
  float* ssm_out_st  = conv_out_st + (size_t)LNUM*BNUM*CONVNUM*KNUM;

  float* ws    = (float*)d_ws;
  float* h     = ws;                  // B*D      = 16384
  float* hn    = h     + 16384;       // B*D      = 16384
  float* proj  = hn    + 16384;       // B*P      = 114432
  float* cvo   = proj  + 114432;      // B*CONV   = 49152
  float* y     = cvo   + 49152;       // B*I      = 32768
  float* yn    = y     + 32768;       // B*I      = 32768
  float* hf    = yn    + 32768;       // B*D      = 16384
  float* part1 = hf    + 16384;       // 16*B*P   = 1830912
  float* part2 = part1 + 1830912;     // 64*B*D   = 1048576
  // total ws: ~12.6 MB

  k_embed<<<BNUM, 256, 0, stream>>>(ids, emb, h);

  for (int l = 0; l < LNUM; ++l){
    k_rmsnorm<<<BNUM, 256, 0, stream>>>(h, hn, norm_w + (size_t)l*DNUM, DNUM);
    dim3 g1(IP_PB, IP_DC);
    k_inproj<<<g1, 256, 0, stream>>>(hn, in_proj_w + (size_t)l*DNUM*PNUM, part1);
    k_reduce_proj<<<(BNUM*PNUM)/256, 256, 0, stream>>>(part1, proj);
    k_conv<<<(BNUM*CONVNUM)/256, 256, 0, stream>>>(
        conv_states + (size_t)l*BNUM*CONVNUM*KNUM, proj,
        conv_w + (size_t)l*CONVNUM*KNUM, conv_b + (size_t)l*CONVNUM,
        conv_out_st + (size_t)l*BNUM*CONVNUM*KNUM, cvo);
    k_ssm<<<BNUM*HNUM, 256, 0, stream>>>(
        ssm_states + (size_t)l*BNUM*HNUM*HDNUM*NNUM, proj, cvo,
        dt_bias + (size_t)l*HNUM, A_log + (size_t)l*HNUM, D_param + (size_t)l*HNUM,
        ssm_out_st + (size_t)l*BNUM*HNUM*HDNUM*NNUM, y);
    k_gatednorm<<<BNUM, 256, 0, stream>>>(proj, y, gn_w + (size_t)l*INUM, yn);
    dim3 g2(4, OP_DC);
    k_outproj<<<g2, 128, 0, stream>>>(yn, out_proj_w + (size_t)l*INUM*DNUM, part2);
    k_reduce_out<<<(BNUM*DNUM)/256, 256, 0, stream>>>(part2, h);
  }

  k_rmsnorm<<<BNUM, 256, 0, stream>>>(h, hf, norm_f_w, DNUM);
  k_lmhead<<<VNUM/16, 256, 0, stream>>>(hf, lm_head_w, logits);
}